// Round 1
// baseline (627.917 us; speedup 1.0000x reference)
//
#include <hip/hip_runtime.h>
#include <stdint.h>

#define NFIELD 20
#define HID 1024
#define KEXP 16
#define KX 1280   // nfield * data_nemb
#define KS 320    // nfield * sql_nemb
#define BATCH 8192

typedef __bf16 bf16x8 __attribute__((ext_vector_type(8)));
typedef float f32x4 __attribute__((ext_vector_type(4)));

__device__ __forceinline__ unsigned short f2bf(float f) {
  union { float f; unsigned u; } v; v.f = f;
  unsigned r = v.u + 0x7FFFu + ((v.u >> 16) & 1u);  // RNE
  return (unsigned short)(r >> 16);
}

__device__ __forceinline__ void gload16(const void* g, void* l) {
  __builtin_amdgcn_global_load_lds(
      (const __attribute__((address_space(1))) unsigned int*)(uintptr_t)g,
      (__attribute__((address_space(3))) unsigned int*)(unsigned)(uintptr_t)l,
      16, 0, 0);
}

// ---------------- prep kernels ----------------

// transpose [R][C] f32 -> [C][R] bf16 (per batch z)
__global__ void transpose_cvt(const float* __restrict__ src, unsigned short* __restrict__ dst,
                              int R, int C, long sstride, long dstride) {
  __shared__ float tile[32][33];
  const float* s = src + (size_t)blockIdx.z * sstride;
  unsigned short* d = dst + (size_t)blockIdx.z * dstride;
  const int r0 = blockIdx.y * 32, c0 = blockIdx.x * 32;
  const int tx = threadIdx.x & 31, ty = threadIdx.x >> 5;  // ty 0..7
#pragma unroll
  for (int i = 0; i < 4; ++i)
    tile[ty + 8 * i][tx] = s[(size_t)(r0 + ty + 8 * i) * C + c0 + tx];
  __syncthreads();
#pragma unroll
  for (int i = 0; i < 4; ++i)
    d[(size_t)(c0 + ty + 8 * i) * R + r0 + tx] = f2bf(tile[tx][ty + 8 * i]);
}

// x_emb[b, f*64+e] = bf16(tab[x[b,f]][e]);  grid=B, block=320 (20 fields * 16 quads)
__global__ void gather_x_k(const int* __restrict__ x, const float* __restrict__ tab,
                           unsigned short* __restrict__ out) {
  const int b = blockIdx.x;
  const int f = threadIdx.x >> 4;
  const int q = threadIdx.x & 15;
  const int idx = x[b * NFIELD + f];
  const float4 v = *(const float4*)(tab + (size_t)idx * 64 + q * 4);
  ushort4 o;
  o.x = f2bf(v.x); o.y = f2bf(v.y); o.z = f2bf(v.z); o.w = f2bf(v.w);
  *(ushort4*)(out + (size_t)b * KX + f * 64 + q * 4) = o;
}

// sql_emb[b, f*16+e];  t = (b,f,q) over 8192*20*4
__global__ void gather_sql_k(const int* __restrict__ sql, const float* __restrict__ tab,
                             unsigned short* __restrict__ out) {
  const int t = blockIdx.x * 256 + threadIdx.x;
  const int b = t / 80;
  const int r = t - b * 80;
  const int f = r >> 2, q = r & 3;
  const int idx = sql[b * NFIELD + f];
  const float4 v = *(const float4*)(tab + (size_t)idx * 16 + q * 4);
  ushort4 o;
  o.x = f2bf(v.x); o.y = f2bf(v.y); o.z = f2bf(v.z); o.w = f2bf(v.w);
  *(ushort4*)(out + (size_t)b * KS + f * 16 + q * 4) = o;
}

// ---------------- fused GEMM: C = A[M,K] * Bt[N,K]^T, epilogue relu(+bias)*W2 -> atomic out ----
// NJO==1 : main experts. n -> expert n>>10; out[row*16 + n0>>10] += sum_col relu(acc+eb1[n])*eW2[n]
// NJO==16: gate.          out[row*16 + jo]   += sum_col relu(acc+gb1[n])*gW2[n*16+jo]
template <int NJO, int KTOT>
__global__ __launch_bounds__(256) void gemm_fused(const __bf16* __restrict__ A,
                                                  const __bf16* __restrict__ Bt,
                                                  const float* __restrict__ bias,
                                                  const float* __restrict__ W2,
                                                  float* __restrict__ out) {
  alignas(16) __shared__ __bf16 As[128][64];
  alignas(16) __shared__ __bf16 Bs[128][64];
  const int tid = threadIdx.x;
  const int lane = tid & 63;
  const int wave = tid >> 6;          // 4 waves
  const int wr = wave >> 1, wc = wave & 1;
  const int m0 = blockIdx.y * 128;
  const int n0 = blockIdx.x * 128;
  // staging: inst i covers 8 rows; lane l -> row rb+l/8, fetches global chunk (l%8)^(l/8)
  // so LDS[r][cc] holds global chunk cc ^ (r&7)  (both-sides swizzle, linear LDS dest)
  const int srow = lane >> 3;
  const int schunk = (lane & 7) ^ srow;
  const int r15 = lane & 15, g4 = lane >> 4;

  f32x4 acc[4][4] = {};

  for (int kt = 0; kt < KTOT / 64; ++kt) {
#pragma unroll
    for (int i = 0; i < 4; ++i) {
      const int rb = wave * 32 + i * 8;
      gload16(A + (size_t)(m0 + rb + srow) * KTOT + kt * 64 + schunk * 8, (void*)&As[rb][0]);
    }
#pragma unroll
    for (int i = 0; i < 4; ++i) {
      const int rb = wave * 32 + i * 8;
      gload16(Bt + (size_t)(n0 + rb + srow) * KTOT + kt * 64 + schunk * 8, (void*)&Bs[rb][0]);
    }
    __syncthreads();  // drains vmcnt (global_load_lds) + barrier
#pragma unroll
    for (int kk = 0; kk < 2; ++kk) {
      bf16x8 af[4], bfr[4];
      const int c = kk * 4 + g4;  // 16B chunk index along K (k = chunk*8..chunk*8+7)
#pragma unroll
      for (int mi = 0; mi < 4; ++mi) {
        const int row = wr * 64 + mi * 16 + r15;
        af[mi] = *(const bf16x8*)&As[row][(c ^ (row & 7)) * 8];
      }
#pragma unroll
      for (int ni = 0; ni < 4; ++ni) {
        const int row = wc * 64 + ni * 16 + r15;
        bfr[ni] = *(const bf16x8*)&Bs[row][(c ^ (row & 7)) * 8];
      }
#pragma unroll
      for (int mi = 0; mi < 4; ++mi)
#pragma unroll
        for (int ni = 0; ni < 4; ++ni)
          acc[mi][ni] = __builtin_amdgcn_mfma_f32_16x16x32_bf16(af[mi], bfr[ni], acc[mi][ni], 0, 0, 0);
    }
    __syncthreads();
  }

  // epilogue: relu(acc + bias), weighted column-reduce, atomic accumulate
  int ncol[4];
  float bsv[4];
#pragma unroll
  for (int ni = 0; ni < 4; ++ni) {
    ncol[ni] = n0 + wc * 64 + ni * 16 + r15;  // C/D: col = lane&15
    bsv[ni] = bias[ncol[ni]];
  }
#pragma unroll
  for (int mi = 0; mi < 4; ++mi)
#pragma unroll
    for (int ni = 0; ni < 4; ++ni)
#pragma unroll
      for (int j = 0; j < 4; ++j) {
        float v = acc[mi][ni][j] + bsv[ni];
        acc[mi][ni][j] = v > 0.f ? v : 0.f;
      }
#pragma unroll
  for (int jo = 0; jo < NJO; ++jo) {
    float w4[4];
#pragma unroll
    for (int ni = 0; ni < 4; ++ni)
      w4[ni] = (NJO == 1) ? W2[ncol[ni]] : W2[ncol[ni] * NJO + jo];
#pragma unroll
    for (int mi = 0; mi < 4; ++mi)
#pragma unroll
      for (int j = 0; j < 4; ++j) {
        float s = acc[mi][0][j] * w4[0] + acc[mi][1][j] * w4[1] +
                  acc[mi][2][j] * w4[2] + acc[mi][3][j] * w4[3];
        s += __shfl_xor(s, 1);
        s += __shfl_xor(s, 2);
        s += __shfl_xor(s, 4);
        s += __shfl_xor(s, 8);
        if (r15 == 0) {
          const int row = m0 + wr * 64 + mi * 16 + g4 * 4 + j;  // C/D: row = (lane>>4)*4 + reg
          const int oc = (NJO == 1) ? (n0 >> 10) : jo;
          atomicAdd(&out[row * KEXP + oc], s);
        }
      }
  }
}

// ---------------- entmax (alpha=1.5, 50 bisect iters) + combine + gate colsums ----------------
__global__ void entmax_combine(const float* __restrict__ gacc, const float* __restrict__ gb2,
                               const float* __restrict__ yk, const float* __restrict__ eb2,
                               float* __restrict__ y, double* __restrict__ colsum) {
  const int b = blockIdx.x * 256 + threadIdx.x;
  float x[16];
  float mx = -3.4e38f;
#pragma unroll
  for (int j = 0; j < 16; ++j) {
    x[j] = (gacc[b * 16 + j] + gb2[j]) * 0.5f;  // * (alpha-1)
    mx = fmaxf(mx, x[j]);
  }
  float lo = mx - 1.0f, hi = mx - 0.25f;  // d^(1-alpha) = 16^-0.5
  float flo = -1.0f;
#pragma unroll
  for (int j = 0; j < 16; ++j) {
    float d = x[j] - lo; d = d > 0.f ? d : 0.f;
    flo += d * d;
  }
  for (int it = 0; it < 50; ++it) {
    const float tm = 0.5f * (lo + hi);
    float fm = -1.0f;
#pragma unroll
    for (int j = 0; j < 16; ++j) {
      float d = x[j] - tm; d = d > 0.f ? d : 0.f;
      fm += d * d;
    }
    if (fm * flo >= 0.f) { lo = tm; flo = fm; } else { hi = tm; }
  }
  const float tm = 0.5f * (lo + hi);
  float p[16], ps = 0.f;
#pragma unroll
  for (int j = 0; j < 16; ++j) {
    float d = x[j] - tm; d = d > 0.f ? d : 0.f;
    p[j] = d * d; ps += p[j];
  }
  const float inv = 1.0f / ps;
  float yv = 0.f;
#pragma unroll
  for (int j = 0; j < 16; ++j) {
    p[j] *= inv;
    yv += p[j] * (yk[b * 16 + j] + eb2[j]);
  }
  y[b] = yv;

  const int lane = threadIdx.x & 63, wv = threadIdx.x >> 6;
  __shared__ float red[4][16];
#pragma unroll
  for (int j = 0; j < 16; ++j) {
    float v = p[j];
    v += __shfl_xor(v, 1);  v += __shfl_xor(v, 2);  v += __shfl_xor(v, 4);
    v += __shfl_xor(v, 8);  v += __shfl_xor(v, 16); v += __shfl_xor(v, 32);
    if (lane == 0) red[wv][j] = v;
  }
  __syncthreads();
  if (threadIdx.x < 16) {
    double s = (double)red[0][threadIdx.x] + (double)red[1][threadIdx.x] +
               (double)red[2][threadIdx.x] + (double)red[3][threadIdx.x];
    atomicAdd(&colsum[threadIdx.x], s);
  }
}

__global__ void loss_k(const double* __restrict__ colsum, float* __restrict__ out) {
  if (threadIdx.x == 0 && blockIdx.x == 0) {
    double m = 0.0;
    for (int k = 0; k < 16; ++k) m += colsum[k];
    m *= (1.0 / 16.0);
    double var = 0.0;
    for (int k = 0; k < 16; ++k) { const double d = colsum[k] - m; var += d * d; }
    var *= (1.0 / 15.0);  // ddof=1
    out[0] = (float)(var / (m * m + 1e-10));
  }
}

// ---------------- launch ----------------
extern "C" void kernel_launch(void* const* d_in, const int* in_sizes, int n_in,
                              void* d_out, int out_size, void* d_ws, size_t ws_size,
                              hipStream_t stream) {
  const int*   x    = (const int*)d_in[0];
  const int*   sql  = (const int*)d_in[1];
  const float* sqlT = (const float*)d_in[2];
  const float* inT  = (const float*)d_in[3];
  const float* gW1  = (const float*)d_in[4];
  const float* gb1  = (const float*)d_in[5];
  const float* gW2  = (const float*)d_in[6];
  const float* gb2  = (const float*)d_in[7];
  const float* eW1  = (const float*)d_in[8];
  const float* eb1  = (const float*)d_in[9];
  const float* eW2  = (const float*)d_in[10];
  const float* eb2  = (const float*)d_in[11];

  char* ws = (char*)d_ws;
  unsigned short* eW1T = (unsigned short*)(ws);              // [16*1024][1280] bf16  41,943,040 B
  unsigned short* xemb = (unsigned short*)(ws + 41943040);   // [8192][1280]          20,971,520 B
  unsigned short* semb = (unsigned short*)(ws + 62914560);   // [8192][320]            5,242,880 B
  unsigned short* gW1T = (unsigned short*)(ws + 68157440);   // [1024][320]              655,360 B
  float*  yk     = (float*)(ws + 68812800);                  // [8192][16]               524,288 B
  float*  gacc   = (float*)(ws + 69337088);                  // [8192][16]               524,288 B
  double* colsum = (double*)(ws + 69861376);                 // [16]                         128 B

  hipMemsetAsync(yk, 0, 524288 * 2 + 128, stream);

  transpose_cvt<<<dim3(32, 40, 16), 256, 0, stream>>>(eW1, eW1T, 1280, 1024, 1280L * 1024, 1024L * 1280);
  transpose_cvt<<<dim3(32, 10, 1), 256, 0, stream>>>(gW1, gW1T, 320, 1024, 0, 0);
  gather_x_k<<<BATCH, 320, 0, stream>>>(x, inT, xemb);
  gather_sql_k<<<BATCH * 80 / 256, 256, 0, stream>>>(sql, sqlT, semb);

  gemm_fused<1, KX><<<dim3(16384 / 128, BATCH / 128), 256, 0, stream>>>(
      (const __bf16*)xemb, (const __bf16*)eW1T, eb1, eW2, yk);
  gemm_fused<16, KS><<<dim3(HID / 128, BATCH / 128), 256, 0, stream>>>(
      (const __bf16*)semb, (const __bf16*)gW1T, gb1, gW2, gacc);

  entmax_combine<<<BATCH / 256, 256, 0, stream>>>(gacc, gb2, yk, eb2, (float*)d_out, colsum);
  loss_k<<<1, 64, 0, stream>>>(colsum, (float*)d_out + BATCH);
}

// Round 2
// 594.346 us; speedup vs baseline: 1.0565x; 1.0565x over previous
//
#include <hip/hip_runtime.h>
#include <stdint.h>

#define NFIELD 20
#define HID 1024
#define KEXP 16
#define KX 1280   // nfield * data_nemb
#define KS 320    // nfield * sql_nemb
#define BATCH 8192

typedef __bf16 bf16x8 __attribute__((ext_vector_type(8)));
typedef float f32x4 __attribute__((ext_vector_type(4)));

__device__ __forceinline__ unsigned short f2bf(float f) {
  union { float f; unsigned u; } v; v.f = f;
  unsigned r = v.u + 0x7FFFu + ((v.u >> 16) & 1u);  // RNE
  return (unsigned short)(r >> 16);
}

__device__ __forceinline__ void gload16(const void* g, void* l) {
  __builtin_amdgcn_global_load_lds(
      (const __attribute__((address_space(1))) unsigned int*)(uintptr_t)g,
      (__attribute__((address_space(3))) unsigned int*)(unsigned)(uintptr_t)l,
      16, 0, 0);
}

#define SBAR() asm volatile("s_barrier" ::: "memory")

// ---------------- prep kernels ----------------

__global__ void transpose_cvt(const float* __restrict__ src, unsigned short* __restrict__ dst,
                              int R, int C, long sstride, long dstride) {
  __shared__ float tile[32][33];
  const float* s = src + (size_t)blockIdx.z * sstride;
  unsigned short* d = dst + (size_t)blockIdx.z * dstride;
  const int r0 = blockIdx.y * 32, c0 = blockIdx.x * 32;
  const int tx = threadIdx.x & 31, ty = threadIdx.x >> 5;
#pragma unroll
  for (int i = 0; i < 4; ++i)
    tile[ty + 8 * i][tx] = s[(size_t)(r0 + ty + 8 * i) * C + c0 + tx];
  __syncthreads();
#pragma unroll
  for (int i = 0; i < 4; ++i)
    d[(size_t)(c0 + ty + 8 * i) * R + r0 + tx] = f2bf(tile[tx][ty + 8 * i]);
}

__global__ void gather_x_k(const int* __restrict__ x, const float* __restrict__ tab,
                           unsigned short* __restrict__ out) {
  const int b = blockIdx.x;
  const int f = threadIdx.x >> 4;
  const int q = threadIdx.x & 15;
  const int idx = x[b * NFIELD + f];
  const float4 v = *(const float4*)(tab + (size_t)idx * 64 + q * 4);
  ushort4 o;
  o.x = f2bf(v.x); o.y = f2bf(v.y); o.z = f2bf(v.z); o.w = f2bf(v.w);
  *(ushort4*)(out + (size_t)b * KX + f * 64 + q * 4) = o;
}

__global__ void gather_sql_k(const int* __restrict__ sql, const float* __restrict__ tab,
                             unsigned short* __restrict__ out) {
  const int t = blockIdx.x * 256 + threadIdx.x;
  const int b = t / 80;
  const int r = t - b * 80;
  const int f = r >> 2, q = r & 3;
  const int idx = sql[b * NFIELD + f];
  const float4 v = *(const float4*)(tab + (size_t)idx * 16 + q * 4);
  ushort4 o;
  o.x = f2bf(v.x); o.y = f2bf(v.y); o.z = f2bf(v.z); o.w = f2bf(v.w);
  *(ushort4*)(out + (size_t)b * KS + f * 16 + q * 4) = o;
}

// ---------------- 256x256 8-phase fused GEMM ----------------
// C = A[M,K] * Bt[N,K]^T ; epilogue: relu(acc+bias) dot W2 column-slices -> atomic out.
// NJO==1 : experts (out[row*16 + n0>>10]) ; NJO==16 : gate (out[row*16 + jo]).
template <int NJO, int KTOT>
__global__ __launch_bounds__(512, 2) void gemm256(const __bf16* __restrict__ A,
                                                  const __bf16* __restrict__ Bt,
                                                  const float* __restrict__ bias,
                                                  const float* __restrict__ W2,
                                                  float* __restrict__ out) {
  constexpr int NT = KTOT / 64;
  alignas(16) __shared__ __bf16 As[2][256][64];
  alignas(16) __shared__ __bf16 Bs[2][256][64];

  const int tid = threadIdx.x;
  const int lane = tid & 63;
  const int wave = tid >> 6;        // 0..7
  const int wr = wave >> 2;         // 0..1 : M half (128 rows)
  const int wc = wave & 3;          // 0..3 : N quarter (64 cols)

  // XCD-aware swizzle (nwg % 8 == 0 for both instantiations)
  unsigned flat = blockIdx.y * gridDim.x + blockIdx.x;
  const unsigned nwg = gridDim.x * gridDim.y;
  flat = (flat & 7u) * (nwg >> 3) + (flat >> 3);
  const int m0 = (int)(flat / gridDim.x) * 256;
  const int n0 = (int)(flat % gridDim.x) * 256;

  const int srow = lane >> 3;
  const int schunk = (lane & 7) ^ srow;   // pre-swizzled global source chunk
  const int r15 = lane & 15, g4 = lane >> 4;

  const __bf16* Ag = A + (size_t)(m0 + srow) * KTOT + schunk * 8;
  const __bf16* Bg = Bt + (size_t)(n0 + srow) * KTOT + schunk * 8;

  auto stageA = [&](int t, int h) {
    const int c = t & 1;
#pragma unroll
    for (int i = 0; i < 2; ++i) {
      const int rb = h * 128 + (wave + 8 * i) * 8;
      gload16(Ag + (size_t)rb * KTOT + t * 64, (void*)&As[c][rb][0]);
    }
  };
  auto stageB = [&](int t, int h) {
    const int c = t & 1;
#pragma unroll
    for (int i = 0; i < 2; ++i) {
      const int rb = h * 128 + (wave + 8 * i) * 8;
      gload16(Bg + (size_t)rb * KTOT + t * 64, (void*)&Bs[c][rb][0]);
    }
  };
  auto rdA = [&](int c, int mi, int kk) -> bf16x8 {
    const int row = wr * 128 + mi * 16 + r15;
    const int ch = (kk * 4 + g4) ^ (row & 7);
    return *(const bf16x8*)&As[c][row][ch * 8];
  };
  auto rdB = [&](int c, int ni, int kk) -> bf16x8 {
    const int row = wc * 64 + ni * 16 + r15;
    const int ch = (kk * 4 + g4) ^ (row & 7);
    return *(const bf16x8*)&Bs[c][row][ch * 8];
  };

  f32x4 acc[8][4] = {};

  // prologue: tile0 fully, B of tile1 (A of tile1 staged during tile0)
  stageA(0, 0); stageA(0, 1);
  stageB(0, 0); stageB(0, 1);
  if (NT > 1) {
    stageB(1, 0); stageB(1, 1);
    asm volatile("s_waitcnt vmcnt(4)" ::: "memory");  // tile0 landed, B(1) in flight
  } else {
    asm volatile("s_waitcnt vmcnt(0)" ::: "memory");
  }
  SBAR();

#pragma unroll 2
  for (int t = 0; t < NT; ++t) {
    const int c = t & 1;
    bf16x8 bfr[4][2];
#pragma unroll
    for (int q = 0; q < 4; ++q) {
      if (q == 0) {
#pragma unroll
        for (int ni = 0; ni < 4; ++ni) {
          bfr[ni][0] = rdB(c, ni, 0);
          bfr[ni][1] = rdB(c, ni, 1);
        }
      }
      bf16x8 af[2][2];
#pragma unroll
      for (int d = 0; d < 2; ++d)
#pragma unroll
        for (int kk = 0; kk < 2; ++kk) af[d][kk] = rdA(c, q * 2 + d, kk);

      if (q == 0 && t + 1 < NT) stageA(t + 1, 0);
      if (q == 1 && t + 1 < NT) stageA(t + 1, 1);
      if (q == 2 && t + 2 < NT) stageB(t + 2, 0);
      if (q == 3 && t + 2 < NT) stageB(t + 2, 1);

      SBAR();
      __builtin_amdgcn_s_setprio(1);
#pragma unroll
      for (int d = 0; d < 2; ++d)
#pragma unroll
        for (int ni = 0; ni < 4; ++ni)
#pragma unroll
          for (int kk = 0; kk < 2; ++kk)
            acc[q * 2 + d][ni] = __builtin_amdgcn_mfma_f32_16x16x32_bf16(
                af[d][kk], bfr[ni][kk], acc[q * 2 + d][ni], 0, 0, 0);
      __builtin_amdgcn_s_setprio(0);
      if (q == 3) {
        if (t < NT - 2) asm volatile("s_waitcnt vmcnt(4)" ::: "memory");
        else            asm volatile("s_waitcnt vmcnt(0)" ::: "memory");
      }
      SBAR();
    }
  }

  // epilogue: relu(acc+bias), weighted column reduce, atomic accumulate
  int ncol[4];
  float bsv[4];
#pragma unroll
  for (int ni = 0; ni < 4; ++ni) {
    ncol[ni] = n0 + wc * 64 + ni * 16 + r15;  // C/D: col = lane&15
    bsv[ni] = bias[ncol[ni]];
  }
#pragma unroll
  for (int mi = 0; mi < 8; ++mi)
#pragma unroll
    for (int ni = 0; ni < 4; ++ni)
#pragma unroll
      for (int j = 0; j < 4; ++j) {
        float v = acc[mi][ni][j] + bsv[ni];
        acc[mi][ni][j] = v > 0.f ? v : 0.f;
      }
#pragma unroll
  for (int jo = 0; jo < NJO; ++jo) {
    float w4[4];
#pragma unroll
    for (int ni = 0; ni < 4; ++ni)
      w4[ni] = (NJO == 1) ? W2[ncol[ni]] : W2[ncol[ni] * NJO + jo];
#pragma unroll
    for (int mi = 0; mi < 8; ++mi)
#pragma unroll
      for (int j = 0; j < 4; ++j) {
        float s = acc[mi][0][j] * w4[0] + acc[mi][1][j] * w4[1] +
                  acc[mi][2][j] * w4[2] + acc[mi][3][j] * w4[3];
        s += __shfl_xor(s, 1);
        s += __shfl_xor(s, 2);
        s += __shfl_xor(s, 4);
        s += __shfl_xor(s, 8);
        if (r15 == 0) {
          const int row = m0 + wr * 128 + mi * 16 + g4 * 4 + j;  // C/D: row=(lane>>4)*4+reg
          const int oc = (NJO == 1) ? (n0 >> 10) : jo;
          atomicAdd(&out[row * KEXP + oc], s);
        }
      }
  }
}

// ---------------- entmax (alpha=1.5, 50 bisect iters) + combine + gate colsums ------------
__global__ void entmax_combine(const float* __restrict__ gacc, const float* __restrict__ gb2,
                               const float* __restrict__ yk, const float* __restrict__ eb2,
                               float* __restrict__ y, double* __restrict__ colsum) {
  const int b = blockIdx.x * 256 + threadIdx.x;
  float x[16];
  float mx = -3.4e38f;
#pragma unroll
  for (int j = 0; j < 16; ++j) {
    x[j] = (gacc[b * 16 + j] + gb2[j]) * 0.5f;  // * (alpha-1)
    mx = fmaxf(mx, x[j]);
  }
  float lo = mx - 1.0f, hi = mx - 0.25f;  // d^(1-alpha) = 16^-0.5
  float flo = -1.0f;
#pragma unroll
  for (int j = 0; j < 16; ++j) {
    float d = x[j] - lo; d = d > 0.f ? d : 0.f;
    flo += d * d;
  }
  for (int it = 0; it < 50; ++it) {
    const float tm = 0.5f * (lo + hi);
    float fm = -1.0f;
#pragma unroll
    for (int j = 0; j < 16; ++j) {
      float d = x[j] - tm; d = d > 0.f ? d : 0.f;
      fm += d * d;
    }
    if (fm * flo >= 0.f) { lo = tm; flo = fm; } else { hi = tm; }
  }
  const float tm = 0.5f * (lo + hi);
  float p[16], ps = 0.f;
#pragma unroll
  for (int j = 0; j < 16; ++j) {
    float d = x[j] - tm; d = d > 0.f ? d : 0.f;
    p[j] = d * d; ps += p[j];
  }
  const float inv = 1.0f / ps;
  float yv = 0.f;
#pragma unroll
  for (int j = 0; j < 16; ++j) {
    p[j] *= inv;
    yv += p[j] * (yk[b * 16 + j] + eb2[j]);
  }
  y[b] = yv;

  const int lane = threadIdx.x & 63, wv = threadIdx.x >> 6;
  __shared__ float red[4][16];
#pragma unroll
  for (int j = 0; j < 16; ++j) {
    float v = p[j];
    v += __shfl_xor(v, 1);  v += __shfl_xor(v, 2);  v += __shfl_xor(v, 4);
    v += __shfl_xor(v, 8);  v += __shfl_xor(v, 16); v += __shfl_xor(v, 32);
    if (lane == 0) red[wv][j] = v;
  }
  __syncthreads();
  if (threadIdx.x < 16) {
    double s = (double)red[0][threadIdx.x] + (double)red[1][threadIdx.x] +
               (double)red[2][threadIdx.x] + (double)red[3][threadIdx.x];
    atomicAdd(&colsum[threadIdx.x], s);
  }
}

__global__ void loss_k(const double* __restrict__ colsum, float* __restrict__ out) {
  if (threadIdx.x == 0 && blockIdx.x == 0) {
    double m = 0.0;
    for (int k = 0; k < 16; ++k) m += colsum[k];
    m *= (1.0 / 16.0);
    double var = 0.0;
    for (int k = 0; k < 16; ++k) { const double d = colsum[k] - m; var += d * d; }
    var *= (1.0 / 15.0);  // ddof=1
    out[0] = (float)(var / (m * m + 1e-10));
  }
}

// ---------------- launch ----------------
extern "C" void kernel_launch(void* const* d_in, const int* in_sizes, int n_in,
                              void* d_out, int out_size, void* d_ws, size_t ws_size,
                              hipStream_t stream) {
  const int*   x    = (const int*)d_in[0];
  const int*   sql  = (const int*)d_in[1];
  const float* sqlT = (const float*)d_in[2];
  const float* inT  = (const float*)d_in[3];
  const float* gW1  = (const float*)d_in[4];
  const float* gb1  = (const float*)d_in[5];
  const float* gW2  = (const float*)d_in[6];
  const float* gb2  = (const float*)d_in[7];
  const float* eW1  = (const float*)d_in[8];
  const float* eb1  = (const float*)d_in[9];
  const float* eW2  = (const float*)d_in[10];
  const float* eb2  = (const float*)d_in[11];

  char* ws = (char*)d_ws;
  unsigned short* eW1T = (unsigned short*)(ws);              // [16384][1280] bf16
  unsigned short* xemb = (unsigned short*)(ws + 41943040);   // [8192][1280]
  unsigned short* semb = (unsigned short*)(ws + 62914560);   // [8192][320]
  unsigned short* gW1T = (unsigned short*)(ws + 68157440);   // [1024][320]
  float*  yk     = (float*)(ws + 68812800);                  // [8192][16]
  float*  gacc   = (float*)(ws + 69337088);                  // [8192][16]
  double* colsum = (double*)(ws + 69861376);                 // [16]

  hipMemsetAsync(yk, 0, 524288 * 2 + 128, stream);

  transpose_cvt<<<dim3(32, 40, 16), 256, 0, stream>>>(eW1, eW1T, 1280, 1024, 1280L * 1024, 1024L * 1280);
  transpose_cvt<<<dim3(32, 10, 1), 256, 0, stream>>>(gW1, gW1T, 320, 1024, 0, 0);
  gather_x_k<<<BATCH, 320, 0, stream>>>(x, inT, xemb);
  gather_sql_k<<<BATCH * 80 / 256, 256, 0, stream>>>(sql, sqlT, semb);

  gemm256<1, KX><<<dim3(16384 / 256, BATCH / 256), 512, 0, stream>>>(
      (const __bf16*)xemb, (const __bf16*)eW1T, eb1, eW2, yk);
  gemm256<16, KS><<<dim3(HID / 256, BATCH / 256), 512, 0, stream>>>(
      (const __bf16*)semb, (const __bf16*)gW1T, gb1, gW2, gacc);

  entmax_combine<<<BATCH / 256, 256, 0, stream>>>(gacc, gb2, yk, eb2, (float*)d_out, colsum);
  loss_k<<<1, 64, 0, stream>>>(colsum, (float*)d_out + BATCH);
}